// Round 2
// baseline (354.944 us; speedup 1.0000x reference)
//
#include <hip/hip_runtime.h>
#include <hip/hip_bf16.h>

// C[M,N] = A[M,K] @ B[N,K]^T. A stays fp32 (staged to LDS via global_load_lds,
// converted to bf16 in the fragment reader); B pre-converted to bf16 in d_ws.
// 128x64 tile, BK=32, 1024 blocks (4/CU), XOR-swizzled LDS (bank-conflict-free).

typedef __bf16 bf16x8 __attribute__((ext_vector_type(8)));
typedef float f32x4 __attribute__((ext_vector_type(4)));

#define TM 128
#define TN 64
#define BK 32

__device__ __forceinline__ void load_lds16(const void* g, void* l) {
    __builtin_amdgcn_global_load_lds(
        (const __attribute__((address_space(1))) void*)g,
        (__attribute__((address_space(3))) void*)l,
        16 /*bytes*/, 0 /*offset*/, 0 /*aux*/);
}

__device__ __forceinline__ bf16x8 cvt8(float4 lo, float4 hi) {
    union { __hip_bfloat162 h2[4]; bf16x8 v; } o;
    o.h2[0] = __float22bfloat162_rn(make_float2(lo.x, lo.y));
    o.h2[1] = __float22bfloat162_rn(make_float2(lo.z, lo.w));
    o.h2[2] = __float22bfloat162_rn(make_float2(hi.x, hi.y));
    o.h2[3] = __float22bfloat162_rn(make_float2(hi.z, hi.w));
    return o.v;
}

__global__ void cvt_f32_to_bf16(const float* __restrict__ src,
                                __hip_bfloat16* __restrict__ dst, int n8) {
    int i = blockIdx.x * blockDim.x + threadIdx.x;
    if (i >= n8) return;
    const float4* p = (const float4*)src + (size_t)i * 2;
    float4 a = p[0];
    float4 b = p[1];
    union { __hip_bfloat16 h[8]; uint4 u; } o;
    o.h[0] = __float2bfloat16(a.x); o.h[1] = __float2bfloat16(a.y);
    o.h[2] = __float2bfloat16(a.z); o.h[3] = __float2bfloat16(a.w);
    o.h[4] = __float2bfloat16(b.x); o.h[5] = __float2bfloat16(b.y);
    o.h[6] = __float2bfloat16(b.z); o.h[7] = __float2bfloat16(b.w);
    ((uint4*)dst)[i] = o.u;
}

// LDS layout (both tiles): row-major, but 16B chunk c of row R stored at slot
//   A (fp32, 8 chunks/row of 4 floats): slot = c ^ (R & 7)
//   B (bf16, 4 chunks/row of 8 elems):  slot = c ^ ((R >> 1) & 3)
// => every quarter-wave of a ds_read_b128 covers all 8 bank groups (2-way max).
__global__ __launch_bounds__(256, 4) void gemm_af32_bbf16(
    const float* __restrict__ A,   // [M,K] fp32
    const __bf16* __restrict__ B,  // [N,K] bf16
    float* __restrict__ C,         // [M,N] fp32
    int M, int N, int K) {
    __shared__ float As[TM * BK];   // 16 KiB
    __shared__ __bf16 Bs[TN * BK];  // 4 KiB

    const int tid = threadIdx.x;
    const int wave = tid >> 6;
    const int lane = tid & 63;
    const int bn = blockIdx.x;
    const int bm = blockIdx.y;

    // ---- A staging: 4 rounds/k-step; wave w round t -> rows t*32 + w*8 + (lane>>3)
    const int aRow = lane >> 3;               // 0..7  (= row & 7)
    const int aCh  = (lane & 7) ^ aRow;       // swizzled global chunk index
    const float* ga = A + ((size_t)bm * TM + wave * 8 + aRow) * (size_t)K + aCh * 4;
    float* la = As + (wave * 8) * BK;         // lane*16B appended by HW

    // ---- B staging: 1 round; wave w -> rows w*16 + (lane>>2)
    const int bRow = lane >> 2;               // 0..15
    const int bCh  = (lane & 3) ^ ((lane >> 3) & 3);
    const __bf16* gb = B + ((size_t)bn * TN + wave * 16 + bRow) * (size_t)K + bCh * 8;
    __bf16* lb = Bs + (wave * 16) * BK;

    // ---- fragment addressing (wave tile 64x32: wm in {0,64}, wn in {0,32})
    const int wm = (wave >> 1) * 64;
    const int wn = (wave & 1) * 32;
    const int fr = lane & 15;
    const int qd = lane >> 4;
    const int slotA = (2 * qd) ^ (fr & 7);        // chunk 2*qd of row (..&7 == fr&7)
    const int slotB = qd ^ ((fr >> 1) & 3);

    f32x4 acc[4][2];
#pragma unroll
    for (int i = 0; i < 4; ++i)
#pragma unroll
        for (int j = 0; j < 2; ++j) acc[i][j] = (f32x4){0.f, 0.f, 0.f, 0.f};

    for (int k0 = 0; k0 < K; k0 += BK) {
#pragma unroll
        for (int t = 0; t < 4; ++t)
            load_lds16(ga + (size_t)(t * 32) * K + k0, la + t * 32 * BK);
        load_lds16(gb + k0, lb);
        __syncthreads();

        bf16x8 af[4], bfr[2];
#pragma unroll
        for (int i = 0; i < 4; ++i) {
            const float* p = As + (wm + i * 16 + fr) * BK;
            float4 lo = *(const float4*)(p + slotA * 4);
            float4 hi = *(const float4*)(p + (slotA ^ 1) * 4);
            af[i] = cvt8(lo, hi);
        }
#pragma unroll
        for (int j = 0; j < 2; ++j)
            bfr[j] = *(const bf16x8*)(Bs + (wn + j * 16 + fr) * BK + slotB * 8);

#pragma unroll
        for (int i = 0; i < 4; ++i)
#pragma unroll
            for (int j = 0; j < 2; ++j)
                acc[i][j] = __builtin_amdgcn_mfma_f32_16x16x32_bf16(
                    af[i], bfr[j], acc[i][j], 0, 0, 0);
        __syncthreads();
    }

    // ---- epilogue: C/D layout col=lane&15, row=(lane>>4)*4+reg
    const int cq = qd * 4;
    float* Cb = C + ((size_t)bm * TM + wm + cq) * (size_t)N + (size_t)bn * TN + wn + fr;
#pragma unroll
    for (int i = 0; i < 4; ++i)
#pragma unroll
        for (int r = 0; r < 4; ++r) {
            float* row = Cb + (size_t)(16 * i + r) * N;
#pragma unroll
            for (int j = 0; j < 2; ++j) row[16 * j] = acc[i][j][r];
        }
}

extern "C" void kernel_launch(void* const* d_in, const int* in_sizes, int n_in,
                              void* d_out, int out_size, void* d_ws, size_t ws_size,
                              hipStream_t stream) {
    const float* A = (const float*)d_in[0];  // [M,K] (all_gather = plain reshape)
    const float* B = (const float*)d_in[1];  // [N,K]
    float* C = (float*)d_out;

    const int K = 4096;
    const int aN = in_sizes[0];
    const int bN = in_sizes[1];
    const int M = aN / K;   // 8192
    const int N = bN / K;   // 1024

    __hip_bfloat16* Bbf = (__hip_bfloat16*)d_ws;   // needs bN*2 = 8.4 MB
    cvt_f32_to_bf16<<<bN / 8 / 256, 256, 0, stream>>>(B, Bbf, bN / 8);

    dim3 grid(N / TN, M / TM);  // (16, 64) = 1024 blocks
    gemm_af32_bbf16<<<grid, 256, 0, stream>>>(A, (const __bf16*)Bbf, C, M, N, K);
}

// Round 3
// 345.758 us; speedup vs baseline: 1.0266x; 1.0266x over previous
//
#include <hip/hip_runtime.h>
#include <hip/hip_bf16.h>

// C[M,N] = A[M,K] @ B[N,K]^T, fp32 in/out, bf16 MFMA.
// Phase 1: zero C; convert A,B fp32->bf16 into d_ws.
// Phase 2: 128x128-tile bf16 GEMM, split-K=2 (grid.z), atomicAdd epilogue.
// Rationale: round-1 structure (16 MFMA : 8 ds_read per wave-iter) was good;
// its limit was 512 blocks = 2 blocks/CU co-residency. Split-K=2 -> 4/CU.

typedef __bf16 bf16x8 __attribute__((ext_vector_type(8)));
typedef float f32x4 __attribute__((ext_vector_type(4)));

#define TM 128
#define TN 128
#define BK 32

__device__ __forceinline__ void load_lds16(const void* g, void* l) {
    __builtin_amdgcn_global_load_lds(
        (const __attribute__((address_space(1))) void*)g,
        (__attribute__((address_space(3))) void*)l,
        16 /*bytes*/, 0 /*offset*/, 0 /*aux*/);
}

__global__ void zero_f32(float* __restrict__ p, int n4) {
    int i = blockIdx.x * blockDim.x + threadIdx.x;
    if (i < n4) ((float4*)p)[i] = make_float4(0.f, 0.f, 0.f, 0.f);
}

__global__ void cvt_f32_to_bf16(const float* __restrict__ src,
                                __hip_bfloat16* __restrict__ dst, int n8) {
    int i = blockIdx.x * blockDim.x + threadIdx.x;
    if (i >= n8) return;
    const float4* p = (const float4*)src + (size_t)i * 2;
    float4 a = p[0];
    float4 b = p[1];
    union { __hip_bfloat16 h[8]; uint4 u; } o;
    o.h[0] = __float2bfloat16(a.x); o.h[1] = __float2bfloat16(a.y);
    o.h[2] = __float2bfloat16(a.z); o.h[3] = __float2bfloat16(a.w);
    o.h[4] = __float2bfloat16(b.x); o.h[5] = __float2bfloat16(b.y);
    o.h[6] = __float2bfloat16(b.z); o.h[7] = __float2bfloat16(b.w);
    ((uint4*)dst)[i] = o.u;
}

// 128x128 tile, BK=32, 256 threads (4 waves 2x2), wave tile 64x64 = 4x4 MFMAs.
// grid.z = split-K index (each half: K/2 = 64 iters). Epilogue: atomicAdd.
__global__ __launch_bounds__(256, 4) void gemm_bt_bf16_sk(
    const __bf16* __restrict__ A,  // [M,K] bf16
    const __bf16* __restrict__ B,  // [N,K] bf16
    float* __restrict__ C,         // [M,N] fp32 (pre-zeroed)
    int M, int N, int K) {
    __shared__ __bf16 As[TM * BK];  // 8 KiB
    __shared__ __bf16 Bs[TN * BK];  // 8 KiB

    const int tid = threadIdx.x;
    const int wave = tid >> 6;
    const int lane = tid & 63;
    const int bn = blockIdx.x;
    const int bm = blockIdx.y;
    const int kz = blockIdx.z;          // 0 or 1
    const int kBeg = kz * (K >> 1);
    const int kEnd = kBeg + (K >> 1);

    // ---- staging: wave covers 16 rows/round, lane -> (row, k-quarter)
    const int srow = lane >> 2;            // 0..15
    const int scol = (lane & 3) << 3;      // bf16 elems 0,8,16,24
    const __bf16* ga = A + ((size_t)bm * TM + wave * 16 + srow) * (size_t)K + scol;
    const __bf16* gb = B + ((size_t)bn * TN + wave * 16 + srow) * (size_t)K + scol;
    const size_t g64 = (size_t)64 * K;
    __bf16* la = As + wave * 512;          // 1024 B per wave per round
    __bf16* lb = Bs + wave * 512;

    // ---- fragment addressing
    const int wm = (wave >> 1) << 6;
    const int wn = (wave & 1) << 6;
    const int fr = lane & 15;
    const int fk = (lane >> 4) << 3;
    const __bf16* pa = As + (wm + fr) * BK + fk;
    const __bf16* pb = Bs + (wn + fr) * BK + fk;

    f32x4 acc[4][4];
#pragma unroll
    for (int i = 0; i < 4; ++i)
#pragma unroll
        for (int j = 0; j < 4; ++j) acc[i][j] = (f32x4){0.f, 0.f, 0.f, 0.f};

    for (int k0 = kBeg; k0 < kEnd; k0 += BK) {
        load_lds16(ga + k0, la);
        load_lds16(ga + g64 + k0, la + 2048);
        load_lds16(gb + k0, lb);
        load_lds16(gb + g64 + k0, lb + 2048);
        __syncthreads();

        bf16x8 af[4], bf[4];
#pragma unroll
        for (int i = 0; i < 4; ++i) af[i] = *(const bf16x8*)(pa + i * (16 * BK));
#pragma unroll
        for (int j = 0; j < 4; ++j) bf[j] = *(const bf16x8*)(pb + j * (16 * BK));
#pragma unroll
        for (int i = 0; i < 4; ++i)
#pragma unroll
            for (int j = 0; j < 4; ++j)
                acc[i][j] = __builtin_amdgcn_mfma_f32_16x16x32_bf16(
                    af[i], bf[j], acc[i][j], 0, 0, 0);
        __syncthreads();
    }

    // ---- epilogue: C/D layout col=lane&15, row=(lane>>4)*4+reg  [m89/m91]
    const int cq = (lane >> 4) << 2;
    const int cc = lane & 15;
    float* Cbase = C + ((size_t)bm * TM + wm + cq) * (size_t)N + (size_t)bn * TN + wn + cc;
#pragma unroll
    for (int i = 0; i < 4; ++i)
#pragma unroll
        for (int r = 0; r < 4; ++r) {
            float* row = Cbase + (size_t)(16 * i + r) * N;
#pragma unroll
            for (int j = 0; j < 4; ++j)
                unsafeAtomicAdd(row + 16 * j, acc[i][j][r]);  // global_atomic_add_f32
        }
}

// Fallback if ws too small: round-1 fused-convert GEMM, plain stores.
__global__ __launch_bounds__(256, 2) void gemm_bt_f32in(
    const float* __restrict__ A, const float* __restrict__ B,
    float* __restrict__ C, int M, int N, int K) {
    __shared__ __bf16 As[TM * BK];
    __shared__ __bf16 Bs[TN * BK];

    const int tid = threadIdx.x;
    const int wave = tid >> 6;
    const int lane = tid & 63;
    const int bn = blockIdx.x;
    const int bm = blockIdx.y;

    const int frow = tid >> 3;
    const int fcol = (tid & 7) << 2;
    const float* gaf = A + ((size_t)bm * TM + frow) * (size_t)K + fcol;
    const float* gbf = B + ((size_t)bn * TN + frow) * (size_t)K + fcol;

    const int wm = (wave >> 1) << 6;
    const int wn = (wave & 1) << 6;
    const int fr = lane & 15;
    const int fk = (lane >> 4) << 3;
    const __bf16* pa = As + (wm + fr) * BK + fk;
    const __bf16* pb = Bs + (wn + fr) * BK + fk;

    f32x4 acc[4][4];
#pragma unroll
    for (int i = 0; i < 4; ++i)
#pragma unroll
        for (int j = 0; j < 4; ++j) acc[i][j] = (f32x4){0.f, 0.f, 0.f, 0.f};

    for (int k0 = 0; k0 < K; k0 += BK) {
#pragma unroll
        for (int rd = 0; rd < 4; ++rd) {
            float4 va = *(const float4*)(gaf + (size_t)(rd * 32) * K + k0);
            float4 vb = *(const float4*)(gbf + (size_t)(rd * 32) * K + k0);
            union { __hip_bfloat16 h[4]; uint2 u; } oa, ob;
            oa.h[0] = __float2bfloat16(va.x); oa.h[1] = __float2bfloat16(va.y);
            oa.h[2] = __float2bfloat16(va.z); oa.h[3] = __float2bfloat16(va.w);
            ob.h[0] = __float2bfloat16(vb.x); ob.h[1] = __float2bfloat16(vb.y);
            ob.h[2] = __float2bfloat16(vb.z); ob.h[3] = __float2bfloat16(vb.w);
            *(uint2*)(As + (frow + rd * 32) * BK + fcol) = oa.u;
            *(uint2*)(Bs + (frow + rd * 32) * BK + fcol) = ob.u;
        }
        __syncthreads();

        bf16x8 af[4], bf[4];
#pragma unroll
        for (int i = 0; i < 4; ++i) af[i] = *(const bf16x8*)(pa + i * (16 * BK));
#pragma unroll
        for (int j = 0; j < 4; ++j) bf[j] = *(const bf16x8*)(pb + j * (16 * BK));
#pragma unroll
        for (int i = 0; i < 4; ++i)
#pragma unroll
            for (int j = 0; j < 4; ++j)
                acc[i][j] = __builtin_amdgcn_mfma_f32_16x16x32_bf16(
                    af[i], bf[j], acc[i][j], 0, 0, 0);
        __syncthreads();
    }

    const int cq = (lane >> 4) << 2;
    const int cc = lane & 15;
    float* Cbase = C + ((size_t)bm * TM + wm + cq) * (size_t)N + (size_t)bn * TN + wn + cc;
#pragma unroll
    for (int i = 0; i < 4; ++i)
#pragma unroll
        for (int r = 0; r < 4; ++r) {
            float* row = Cbase + (size_t)(16 * i + r) * N;
#pragma unroll
            for (int j = 0; j < 4; ++j) row[16 * j] = acc[i][j][r];
        }
}

extern "C" void kernel_launch(void* const* d_in, const int* in_sizes, int n_in,
                              void* d_out, int out_size, void* d_ws, size_t ws_size,
                              hipStream_t stream) {
    const float* A = (const float*)d_in[0];  // [M,K] (all_gather = reshape)
    const float* B = (const float*)d_in[1];  // [N,K]
    float* C = (float*)d_out;

    const int K = 4096;
    const int aN = in_sizes[0];
    const int bN = in_sizes[1];
    const int M = aN / K;   // 8192
    const int N = bN / K;   // 1024

    const size_t need = ((size_t)aN + (size_t)bN) * sizeof(__hip_bfloat16);

    if (ws_size >= need) {
        __hip_bfloat16* Abf = (__hip_bfloat16*)d_ws;
        __hip_bfloat16* Bbf = Abf + (size_t)aN;
        zero_f32<<<(out_size / 4 + 255) / 256, 256, 0, stream>>>(C, out_size / 4);
        cvt_f32_to_bf16<<<bN / 8 / 256, 256, 0, stream>>>(B, Bbf, bN / 8);
        cvt_f32_to_bf16<<<aN / 8 / 256, 256, 0, stream>>>(A, Abf, aN / 8);
        dim3 grid(N / TN, M / TM, 2);  // (8, 64, 2) = 1024 blocks
        gemm_bt_bf16_sk<<<grid, 256, 0, stream>>>(
            (const __bf16*)Abf, (const __bf16*)Bbf, C, M, N, K);
    } else {
        dim3 grid(N / TN, M / TM);
        gemm_bt_f32in<<<grid, 256, 0, stream>>>(A, B, C, M, N, K);
    }
}

// Round 4
// 335.964 us; speedup vs baseline: 1.0565x; 1.0292x over previous
//
#include <hip/hip_runtime.h>
#include <hip/hip_bf16.h>

// C[M,N] = A[M,K] @ B[N,K]^T, fp32 in/out, bf16 MFMA.
// cvt_B: B fp32->bf16 into d_ws (8.4 MB, ~4 us).
// gemm: 128x128 tile, BK=32. A staged fp32->bf16 IN-KERNEL (global_load_dwordx4
//   + v_cvt_pk + ds_write_b64 — VALU pipe was 90% idle, m114 co-schedule);
//   B staged bf16 via global_load_lds w=16. LDS stays bf16 => LDS bytes/FLOP
//   unchanged vs round 1 (round 2's fp32-LDS mistake avoided).

typedef __bf16 bf16x8 __attribute__((ext_vector_type(8)));
typedef float f32x4 __attribute__((ext_vector_type(4)));

#define TM 128
#define TN 128
#define BK 32

__device__ __forceinline__ void load_lds16(const void* g, void* l) {
    __builtin_amdgcn_global_load_lds(
        (const __attribute__((address_space(1))) void*)g,
        (__attribute__((address_space(3))) void*)l,
        16 /*bytes*/, 0 /*offset*/, 0 /*aux*/);
}

__global__ void cvt_f32_to_bf16(const float* __restrict__ src,
                                __hip_bfloat16* __restrict__ dst, int n8) {
    int i = blockIdx.x * blockDim.x + threadIdx.x;
    if (i >= n8) return;
    const float4* p = (const float4*)src + (size_t)i * 2;
    float4 a = p[0];
    float4 b = p[1];
    union { __hip_bfloat16 h[8]; uint4 u; } o;
    o.h[0] = __float2bfloat16(a.x); o.h[1] = __float2bfloat16(a.y);
    o.h[2] = __float2bfloat16(a.z); o.h[3] = __float2bfloat16(a.w);
    o.h[4] = __float2bfloat16(b.x); o.h[5] = __float2bfloat16(b.y);
    o.h[6] = __float2bfloat16(b.z); o.h[7] = __float2bfloat16(b.w);
    ((uint4*)dst)[i] = o.u;
}

// 128x128 tile, BK=32, 256 threads (4 waves 2x2), wave tile 64x64 = 4x4 MFMAs.
__global__ __launch_bounds__(256, 2) void gemm_afuse_bbf16(
    const float* __restrict__ A,   // [M,K] fp32
    const __bf16* __restrict__ B,  // [N,K] bf16 (pre-converted)
    float* __restrict__ C,         // [M,N] fp32
    int M, int N, int K) {
    __shared__ __bf16 As[TM * BK];  // 8 KiB
    __shared__ __bf16 Bs[TN * BK];  // 8 KiB

    const int tid = threadIdx.x;
    const int wave = tid >> 6;
    const int lane = tid & 63;
    const int bn = blockIdx.x;
    const int bm = blockIdx.y;

    // ---- A staging (fp32 -> bf16 via VALU): thread t -> row t>>3, 4 floats
    const int arow = tid >> 3;             // 0..31... wait, 256/8 = 32 rows? need 128
    // 256 threads, 128 rows x 32 cols fp32 = 4096 float4s... 1024 float4.
    // Each thread: 1 float4 per iter covers 256*4 = 1024 floats = 1/4 tile.
    // => 4 sub-rounds: thread t, round d -> row d*32 + (t>>3), cols (t&7)*4.
    const int ar = tid >> 3;               // 0..31 (row within 32-row group)
    const int ac = (tid & 7) << 2;         // fp32 col 0..28
    const float* ga = A + ((size_t)bm * TM + ar) * (size_t)K + ac;

    // ---- B staging via global_load_lds: wave covers 16 rows/round, 2 rounds
    const int srow = lane >> 2;            // 0..15
    const int scol = (lane & 3) << 3;      // bf16 elems 0,8,16,24
    const __bf16* gb = B + ((size_t)bn * TN + wave * 16 + srow) * (size_t)K + scol;
    const size_t g64 = (size_t)64 * K;
    __bf16* lb = Bs + wave * 512;

    // ---- fragment addressing
    const int wm = (wave >> 1) << 6;
    const int wn = (wave & 1) << 6;
    const int fr = lane & 15;
    const int fk = (lane >> 4) << 3;
    const __bf16* pa = As + (wm + fr) * BK + fk;
    const __bf16* pb = Bs + (wn + fr) * BK + fk;

    f32x4 acc[4][4];
#pragma unroll
    for (int i = 0; i < 4; ++i)
#pragma unroll
        for (int j = 0; j < 4; ++j) acc[i][j] = (f32x4){0.f, 0.f, 0.f, 0.f};

    for (int k0 = 0; k0 < K; k0 += BK) {
        // B: async direct-to-LDS
        load_lds16(gb + k0, lb);
        load_lds16(gb + g64 + k0, lb + 2048);
        // A: fp32 load -> cvt -> bf16 ds_write (4 rounds of 32 rows)
#pragma unroll
        for (int d = 0; d < 4; ++d) {
            float4 v = *(const float4*)(ga + (size_t)(d * 32) * K + k0);
            union { __hip_bfloat162 h2[2]; uint2 u; } o;
            o.h2[0] = __float22bfloat162_rn(make_float2(v.x, v.y));
            o.h2[1] = __float22bfloat162_rn(make_float2(v.z, v.w));
            *(uint2*)(As + (d * 32 + ar) * BK + ac) = o.u;
        }
        __syncthreads();

        bf16x8 af[4], bf[4];
#pragma unroll
        for (int i = 0; i < 4; ++i) af[i] = *(const bf16x8*)(pa + i * (16 * BK));
#pragma unroll
        for (int j = 0; j < 4; ++j) bf[j] = *(const bf16x8*)(pb + j * (16 * BK));
#pragma unroll
        for (int i = 0; i < 4; ++i)
#pragma unroll
            for (int j = 0; j < 4; ++j)
                acc[i][j] = __builtin_amdgcn_mfma_f32_16x16x32_bf16(
                    af[i], bf[j], acc[i][j], 0, 0, 0);
        __syncthreads();
    }

    // ---- epilogue: C/D layout col=lane&15, row=(lane>>4)*4+reg  [m89/m91]
    const int cq = (lane >> 4) << 2;
    const int cc = lane & 15;
    float* Cbase = C + ((size_t)bm * TM + wm + cq) * (size_t)N + (size_t)bn * TN + wn + cc;
#pragma unroll
    for (int i = 0; i < 4; ++i)
#pragma unroll
        for (int r = 0; r < 4; ++r) {
            float* row = Cbase + (size_t)(16 * i + r) * N;
#pragma unroll
            for (int j = 0; j < 4; ++j) row[16 * j] = acc[i][j][r];
        }
}

// Fallback if ws too small: fully fused (both inputs fp32, VALU staging).
__global__ __launch_bounds__(256, 2) void gemm_bt_f32in(
    const float* __restrict__ A, const float* __restrict__ B,
    float* __restrict__ C, int M, int N, int K) {
    __shared__ __bf16 As[TM * BK];
    __shared__ __bf16 Bs[TN * BK];

    const int tid = threadIdx.x;
    const int wave = tid >> 6;
    const int lane = tid & 63;
    const int bn = blockIdx.x;
    const int bm = blockIdx.y;

    const int frow = tid >> 3;
    const int fcol = (tid & 7) << 2;
    const float* gaf = A + ((size_t)bm * TM + frow) * (size_t)K + fcol;
    const float* gbf = B + ((size_t)bn * TN + frow) * (size_t)K + fcol;

    const int wm = (wave >> 1) << 6;
    const int wn = (wave & 1) << 6;
    const int fr = lane & 15;
    const int fk = (lane >> 4) << 3;
    const __bf16* pa = As + (wm + fr) * BK + fk;
    const __bf16* pb = Bs + (wn + fr) * BK + fk;

    f32x4 acc[4][4];
#pragma unroll
    for (int i = 0; i < 4; ++i)
#pragma unroll
        for (int j = 0; j < 4; ++j) acc[i][j] = (f32x4){0.f, 0.f, 0.f, 0.f};

    for (int k0 = 0; k0 < K; k0 += BK) {
#pragma unroll
        for (int rd = 0; rd < 4; ++rd) {
            float4 va = *(const float4*)(gaf + (size_t)(rd * 32) * K + k0);
            float4 vb = *(const float4*)(gbf + (size_t)(rd * 32) * K + k0);
            union { __hip_bfloat162 h2[2]; uint2 u; } oa, ob;
            oa.h2[0] = __float22bfloat162_rn(make_float2(va.x, va.y));
            oa.h2[1] = __float22bfloat162_rn(make_float2(va.z, va.w));
            ob.h2[0] = __float22bfloat162_rn(make_float2(vb.x, vb.y));
            ob.h2[1] = __float22bfloat162_rn(make_float2(vb.z, vb.w));
            *(uint2*)(As + (frow + rd * 32) * BK + fcol) = oa.u;
            *(uint2*)(Bs + (frow + rd * 32) * BK + fcol) = ob.u;
        }
        __syncthreads();

        bf16x8 af[4], bf[4];
#pragma unroll
        for (int i = 0; i < 4; ++i) af[i] = *(const bf16x8*)(pa + i * (16 * BK));
#pragma unroll
        for (int j = 0; j < 4; ++j) bf[j] = *(const bf16x8*)(pb + j * (16 * BK));
#pragma unroll
        for (int i = 0; i < 4; ++i)
#pragma unroll
            for (int j = 0; j < 4; ++j)
                acc[i][j] = __builtin_amdgcn_mfma_f32_16x16x32_bf16(
                    af[i], bf[j], acc[i][j], 0, 0, 0);
        __syncthreads();
    }

    const int cq = (lane >> 4) << 2;
    const int cc = lane & 15;
    float* Cbase = C + ((size_t)bm * TM + wm + cq) * (size_t)N + (size_t)bn * TN + wn + cc;
#pragma unroll
    for (int i = 0; i < 4; ++i)
#pragma unroll
        for (int r = 0; r < 4; ++r) {
            float* row = Cbase + (size_t)(16 * i + r) * N;
#pragma unroll
            for (int j = 0; j < 4; ++j) row[16 * j] = acc[i][j][r];
        }
}

extern "C" void kernel_launch(void* const* d_in, const int* in_sizes, int n_in,
                              void* d_out, int out_size, void* d_ws, size_t ws_size,
                              hipStream_t stream) {
    const float* A = (const float*)d_in[0];  // [M,K] (all_gather = reshape)
    const float* B = (const float*)d_in[1];  // [N,K]
    float* C = (float*)d_out;

    const int K = 4096;
    const int aN = in_sizes[0];
    const int bN = in_sizes[1];
    const int M = aN / K;   // 8192
    const int N = bN / K;   // 1024

    dim3 grid(N / TN, M / TM);  // (8, 64) = 512 blocks

    if (ws_size >= (size_t)bN * sizeof(__hip_bfloat16)) {
        __hip_bfloat16* Bbf = (__hip_bfloat16*)d_ws;
        cvt_f32_to_bf16<<<bN / 8 / 256, 256, 0, stream>>>(B, Bbf, bN / 8);
        gemm_afuse_bbf16<<<grid, 256, 0, stream>>>(
            A, (const __bf16*)Bbf, C, M, N, K);
    } else {
        gemm_bt_f32in<<<grid, 256, 0, stream>>>(A, B, C, M, N, K);
    }
}

// Round 5
// 302.966 us; speedup vs baseline: 1.1716x; 1.1089x over previous
//
#include <hip/hip_runtime.h>
#include <hip/hip_bf16.h>

// C[M,N] = A[M,K] @ B[N,K]^T, fp32 in/out, bf16 MFMA.
// Phase 1: convert A,B fp32->bf16 into d_ws (cvt_A runs at HBM ceiling, keep).
// Phase 2: R1's 128x128 tile GEMM with BK=64: halves barrier count (128->64
//   iters) to amortize the per-barrier vmcnt(0) drain — the measured stall at
//   2 grid-limited blocks/CU. MFMA:ds_read ratio unchanged (2:1).

typedef __bf16 bf16x8 __attribute__((ext_vector_type(8)));
typedef float f32x4 __attribute__((ext_vector_type(4)));

#define TM 128
#define TN 128
#define BK 64

__device__ __forceinline__ void load_lds16(const void* g, void* l) {
    __builtin_amdgcn_global_load_lds(
        (const __attribute__((address_space(1))) void*)g,
        (__attribute__((address_space(3))) void*)l,
        16 /*bytes*/, 0 /*offset*/, 0 /*aux*/);
}

__global__ void cvt_f32_to_bf16(const float* __restrict__ src,
                                __hip_bfloat16* __restrict__ dst, int n8) {
    int i = blockIdx.x * blockDim.x + threadIdx.x;
    if (i >= n8) return;
    const float4* p = (const float4*)src + (size_t)i * 2;
    float4 a = p[0];
    float4 b = p[1];
    union { __hip_bfloat16 h[8]; uint4 u; } o;
    o.h[0] = __float2bfloat16(a.x); o.h[1] = __float2bfloat16(a.y);
    o.h[2] = __float2bfloat16(a.z); o.h[3] = __float2bfloat16(a.w);
    o.h[4] = __float2bfloat16(b.x); o.h[5] = __float2bfloat16(b.y);
    o.h[6] = __float2bfloat16(b.z); o.h[7] = __float2bfloat16(b.w);
    ((uint4*)dst)[i] = o.u;
}

// 128x128 tile, BK=64, 256 threads (4 waves 2x2), wave tile 64x64.
// Per k-iter: 8 async global_load_lds/thread, 16 ds_read_b128/wave, 32 MFMA/wave.
__global__ __launch_bounds__(256, 2) void gemm_bt_bf16_k64(
    const __bf16* __restrict__ A,  // [M,K] bf16
    const __bf16* __restrict__ B,  // [N,K] bf16
    float* __restrict__ C,         // [M,N] fp32
    int M, int N, int K) {
    __shared__ __bf16 As[TM * BK];  // 16 KiB
    __shared__ __bf16 Bs[TN * BK];  // 16 KiB

    const int tid = threadIdx.x;
    const int wave = tid >> 6;
    const int lane = tid & 63;
    const int bn = blockIdx.x;
    const int bm = blockIdx.y;

    // ---- staging: tile row = 64 cols = 128 B; wave covers 8 rows/round,
    //      4 rounds of 32 rows cover 128 rows. lane -> (row, 16B-chunk).
    const int srow = lane >> 3;            // 0..7
    const int scol = (lane & 7) << 3;      // bf16 elem col 0,8,...,56
    const __bf16* ga = A + ((size_t)bm * TM + wave * 8 + srow) * (size_t)K + scol;
    const __bf16* gb = B + ((size_t)bn * TN + wave * 8 + srow) * (size_t)K + scol;
    const size_t g32 = (size_t)32 * K;     // 32-row advance per round
    __bf16* la = As + wave * 512;          // 1024 B per wave per round
    __bf16* lb = Bs + wave * 512;          // round r adds r*2048 elems

    // ---- fragment addressing
    const int wm = (wave >> 1) << 6;
    const int wn = (wave & 1) << 6;
    const int fr = lane & 15;
    const int fk = (lane >> 4) << 3;       // k = quad*8 within a 32-chunk
    const __bf16* pa = As + (wm + fr) * BK + fk;
    const __bf16* pb = Bs + (wn + fr) * BK + fk;

    f32x4 acc[4][4];
#pragma unroll
    for (int i = 0; i < 4; ++i)
#pragma unroll
        for (int j = 0; j < 4; ++j) acc[i][j] = (f32x4){0.f, 0.f, 0.f, 0.f};

    for (int k0 = 0; k0 < K; k0 += BK) {
#pragma unroll
        for (int r = 0; r < 4; ++r) {
            load_lds16(ga + r * g32 + k0, la + r * 2048);
            load_lds16(gb + r * g32 + k0, lb + r * 2048);
        }
        __syncthreads();

        bf16x8 af[2][4], bf[2][4];
#pragma unroll
        for (int c = 0; c < 2; ++c)
#pragma unroll
            for (int i = 0; i < 4; ++i) {
                af[c][i] = *(const bf16x8*)(pa + i * (16 * BK) + c * 32);
                bf[c][i] = *(const bf16x8*)(pb + i * (16 * BK) + c * 32);
            }
#pragma unroll
        for (int c = 0; c < 2; ++c)
#pragma unroll
            for (int i = 0; i < 4; ++i)
#pragma unroll
                for (int j = 0; j < 4; ++j)
                    acc[i][j] = __builtin_amdgcn_mfma_f32_16x16x32_bf16(
                        af[c][i], bf[c][j], acc[i][j], 0, 0, 0);
        __syncthreads();
    }

    // ---- epilogue: C/D layout col=lane&15, row=(lane>>4)*4+reg  [m89/m91]
    const int cq = (lane >> 4) << 2;
    float* Cbase = C + ((size_t)bm * TM + wm + cq) * (size_t)N + (size_t)bn * TN + wn + fr;
#pragma unroll
    for (int i = 0; i < 4; ++i)
#pragma unroll
        for (int r = 0; r < 4; ++r) {
            float* row = Cbase + (size_t)(16 * i + r) * N;
#pragma unroll
            for (int j = 0; j < 4; ++j) row[16 * j] = acc[i][j][r];
        }
}

// Fallback if ws too small: fused-convert GEMM (BK=32), plain stores.
__global__ __launch_bounds__(256, 2) void gemm_bt_f32in(
    const float* __restrict__ A, const float* __restrict__ B,
    float* __restrict__ C, int M, int N, int K) {
    __shared__ __bf16 As[TM * 32];
    __shared__ __bf16 Bs[TN * 32];

    const int tid = threadIdx.x;
    const int wave = tid >> 6;
    const int lane = tid & 63;
    const int bn = blockIdx.x;
    const int bm = blockIdx.y;

    const int frow = tid >> 3;
    const int fcol = (tid & 7) << 2;
    const float* gaf = A + ((size_t)bm * TM + frow) * (size_t)K + fcol;
    const float* gbf = B + ((size_t)bn * TN + frow) * (size_t)K + fcol;

    const int wm = (wave >> 1) << 6;
    const int wn = (wave & 1) << 6;
    const int fr = lane & 15;
    const int fk = (lane >> 4) << 3;
    const __bf16* pa = As + (wm + fr) * 32 + fk;
    const __bf16* pb = Bs + (wn + fr) * 32 + fk;

    f32x4 acc[4][4];
#pragma unroll
    for (int i = 0; i < 4; ++i)
#pragma unroll
        for (int j = 0; j < 4; ++j) acc[i][j] = (f32x4){0.f, 0.f, 0.f, 0.f};

    for (int k0 = 0; k0 < K; k0 += 32) {
#pragma unroll
        for (int rd = 0; rd < 4; ++rd) {
            float4 va = *(const float4*)(gaf + (size_t)(rd * 32) * K + k0);
            float4 vb = *(const float4*)(gbf + (size_t)(rd * 32) * K + k0);
            union { __hip_bfloat162 h2[2]; uint2 u; } oa, ob;
            oa.h2[0] = __float22bfloat162_rn(make_float2(va.x, va.y));
            oa.h2[1] = __float22bfloat162_rn(make_float2(va.z, va.w));
            ob.h2[0] = __float22bfloat162_rn(make_float2(vb.x, vb.y));
            ob.h2[1] = __float22bfloat162_rn(make_float2(vb.z, vb.w));
            *(uint2*)(As + (frow + rd * 32) * 32 + fcol) = oa.u;
            *(uint2*)(Bs + (frow + rd * 32) * 32 + fcol) = ob.u;
        }
        __syncthreads();

        bf16x8 af[4], bf[4];
#pragma unroll
        for (int i = 0; i < 4; ++i) af[i] = *(const bf16x8*)(pa + i * (16 * 32));
#pragma unroll
        for (int j = 0; j < 4; ++j) bf[j] = *(const bf16x8*)(pb + j * (16 * 32));
#pragma unroll
        for (int i = 0; i < 4; ++i)
#pragma unroll
            for (int j = 0; j < 4; ++j)
                acc[i][j] = __builtin_amdgcn_mfma_f32_16x16x32_bf16(
                    af[i], bf[j], acc[i][j], 0, 0, 0);
        __syncthreads();
    }

    const int cq = (lane >> 4) << 2;
    float* Cbase = C + ((size_t)bm * TM + wm + cq) * (size_t)N + (size_t)bn * TN + wn + fr;
#pragma unroll
    for (int i = 0; i < 4; ++i)
#pragma unroll
        for (int r = 0; r < 4; ++r) {
            float* row = Cbase + (size_t)(16 * i + r) * N;
#pragma unroll
            for (int j = 0; j < 4; ++j) row[16 * j] = acc[i][j][r];
        }
}

extern "C" void kernel_launch(void* const* d_in, const int* in_sizes, int n_in,
                              void* d_out, int out_size, void* d_ws, size_t ws_size,
                              hipStream_t stream) {
    const float* A = (const float*)d_in[0];  // [M,K] (all_gather = reshape)
    const float* B = (const float*)d_in[1];  // [N,K]
    float* C = (float*)d_out;

    const int K = 4096;
    const int aN = in_sizes[0];
    const int bN = in_sizes[1];
    const int M = aN / K;   // 8192
    const int N = bN / K;   // 1024

    dim3 grid(N / TN, M / TM);  // (8, 64) = 512 blocks
    const size_t need = ((size_t)aN + (size_t)bN) * sizeof(__hip_bfloat16);

    if (ws_size >= need) {
        __hip_bfloat16* Abf = (__hip_bfloat16*)d_ws;
        __hip_bfloat16* Bbf = Abf + (size_t)aN;
        cvt_f32_to_bf16<<<bN / 8 / 256, 256, 0, stream>>>(B, Bbf, bN / 8);
        cvt_f32_to_bf16<<<aN / 8 / 256, 256, 0, stream>>>(A, Abf, aN / 8);
        gemm_bt_bf16_k64<<<grid, 256, 0, stream>>>(
            (const __bf16*)Abf, (const __bf16*)Bbf, C, M, N, K);
    } else {
        gemm_bt_f32in<<<grid, 256, 0, stream>>>(A, B, C, M, N, K);
    }
}

// Round 6
// 291.577 us; speedup vs baseline: 1.2173x; 1.0391x over previous
//
#include <hip/hip_runtime.h>
#include <hip/hip_bf16.h>

// C[M,N] = A[M,K] @ B[N,K]^T, fp32 in/out, bf16 MFMA.
// Phase 1: convert A,B fp32->bf16 into d_ws (cvt_A runs at HBM ceiling).
// Phase 2: R5's 128x128/BK=64 GEMM + XOR bank-swizzle on 16B chunks:
//   LDS slot(c,row) = c ^ (row&7). Staging lane fetches global chunk
//   (lane&7)^(lane>>3) so HW's base+lane*16 placement lands swizzled;
//   fragment reads use slot (qd+4c)^(fr&7) -> each quarter-wave covers all
//   8 bank groups -> 2-way (free, m136). R1/R5 were conflict-bound
//   (8/16-way, SQ_LDS_BANK_CONFLICT 8.4M/25.2M).

typedef __bf16 bf16x8 __attribute__((ext_vector_type(8)));
typedef float f32x4 __attribute__((ext_vector_type(4)));

#define TM 128
#define TN 128
#define BK 64

__device__ __forceinline__ void load_lds16(const void* g, void* l) {
    __builtin_amdgcn_global_load_lds(
        (const __attribute__((address_space(1))) void*)g,
        (__attribute__((address_space(3))) void*)l,
        16 /*bytes*/, 0 /*offset*/, 0 /*aux*/);
}

__global__ void cvt_f32_to_bf16(const float* __restrict__ src,
                                __hip_bfloat16* __restrict__ dst, int n8) {
    int i = blockIdx.x * blockDim.x + threadIdx.x;
    if (i >= n8) return;
    const float4* p = (const float4*)src + (size_t)i * 2;
    float4 a = p[0];
    float4 b = p[1];
    union { __hip_bfloat16 h[8]; uint4 u; } o;
    o.h[0] = __float2bfloat16(a.x); o.h[1] = __float2bfloat16(a.y);
    o.h[2] = __float2bfloat16(a.z); o.h[3] = __float2bfloat16(a.w);
    o.h[4] = __float2bfloat16(b.x); o.h[5] = __float2bfloat16(b.y);
    o.h[6] = __float2bfloat16(b.z); o.h[7] = __float2bfloat16(b.w);
    ((uint4*)dst)[i] = o.u;
}

// 128x128 tile, BK=64, 256 threads (4 waves 2x2), wave tile 64x64.
__global__ __launch_bounds__(256, 2) void gemm_bt_bf16_sw(
    const __bf16* __restrict__ A,  // [M,K] bf16
    const __bf16* __restrict__ B,  // [N,K] bf16
    float* __restrict__ C,         // [M,N] fp32
    int M, int N, int K) {
    __shared__ __bf16 As[TM * BK];  // 16 KiB
    __shared__ __bf16 Bs[TN * BK];  // 16 KiB

    const int tid = threadIdx.x;
    const int wave = tid >> 6;
    const int lane = tid & 63;
    const int bn = blockIdx.x;
    const int bm = blockIdx.y;

    // ---- staging: row = 128 B = 8 chunks; wave covers 8 rows/round, 4 rounds.
    // lane L -> row (L>>3), fetches global chunk (L&7)^(L>>3) so that the HW
    // placement (base + L*16B) stores chunk c at slot c^(row&7).
    const int srow = lane >> 3;                       // 0..7 == row&7
    const int scol = ((lane & 7) ^ srow) << 3;        // swizzled global col
    const __bf16* ga = A + ((size_t)bm * TM + wave * 8 + srow) * (size_t)K + scol;
    const __bf16* gb = B + ((size_t)bn * TN + wave * 8 + srow) * (size_t)K + scol;
    const size_t g32 = (size_t)32 * K;     // 32-row advance per round
    __bf16* la = As + wave * 512;          // 1 KiB per wave per round
    __bf16* lb = Bs + wave * 512;

    // ---- fragment addressing
    const int wm = (wave >> 1) << 6;
    const int wn = (wave & 1) << 6;
    const int fr = lane & 15;
    const int qd = lane >> 4;              // 0..3
    const int r7 = fr & 7;                 // row&7 for swizzle

    f32x4 acc[4][4];
#pragma unroll
    for (int i = 0; i < 4; ++i)
#pragma unroll
        for (int j = 0; j < 4; ++j) acc[i][j] = (f32x4){0.f, 0.f, 0.f, 0.f};

    for (int k0 = 0; k0 < K; k0 += BK) {
#pragma unroll
        for (int r = 0; r < 4; ++r) {
            load_lds16(ga + r * g32 + k0, la + r * 2048);
            load_lds16(gb + r * g32 + k0, lb + r * 2048);
        }
        __syncthreads();

        bf16x8 af[2][4], bf[2][4];
#pragma unroll
        for (int c = 0; c < 2; ++c) {
            const int slot = ((qd + 4 * c) ^ r7) << 3;  // chunk qd+4c swizzled
#pragma unroll
            for (int i = 0; i < 4; ++i) {
                af[c][i] = *(const bf16x8*)(As + (wm + i * 16 + fr) * BK + slot);
                bf[c][i] = *(const bf16x8*)(Bs + (wn + i * 16 + fr) * BK + slot);
            }
        }
#pragma unroll
        for (int c = 0; c < 2; ++c)
#pragma unroll
            for (int i = 0; i < 4; ++i)
#pragma unroll
                for (int j = 0; j < 4; ++j)
                    acc[i][j] = __builtin_amdgcn_mfma_f32_16x16x32_bf16(
                        af[c][i], bf[c][j], acc[i][j], 0, 0, 0);
        __syncthreads();
    }

    // ---- epilogue: C/D layout col=lane&15, row=(lane>>4)*4+reg  [m89/m91]
    const int cq = qd << 2;
    float* Cbase = C + ((size_t)bm * TM + wm + cq) * (size_t)N + (size_t)bn * TN + wn + fr;
#pragma unroll
    for (int i = 0; i < 4; ++i)
#pragma unroll
        for (int r = 0; r < 4; ++r) {
            float* row = Cbase + (size_t)(16 * i + r) * N;
#pragma unroll
            for (int j = 0; j < 4; ++j) row[16 * j] = acc[i][j][r];
        }
}

// Fallback if ws too small: fused-convert GEMM (BK=32), plain stores.
__global__ __launch_bounds__(256, 2) void gemm_bt_f32in(
    const float* __restrict__ A, const float* __restrict__ B,
    float* __restrict__ C, int M, int N, int K) {
    __shared__ __bf16 As[TM * 32];
    __shared__ __bf16 Bs[TN * 32];

    const int tid = threadIdx.x;
    const int wave = tid >> 6;
    const int lane = tid & 63;
    const int bn = blockIdx.x;
    const int bm = blockIdx.y;

    const int frow = tid >> 3;
    const int fcol = (tid & 7) << 2;
    const float* gaf = A + ((size_t)bm * TM + frow) * (size_t)K + fcol;
    const float* gbf = B + ((size_t)bn * TN + frow) * (size_t)K + fcol;

    const int wm = (wave >> 1) << 6;
    const int wn = (wave & 1) << 6;
    const int fr = lane & 15;
    const int fk = (lane >> 4) << 3;
    const __bf16* pa = As + (wm + fr) * 32 + fk;
    const __bf16* pb = Bs + (wn + fr) * 32 + fk;

    f32x4 acc[4][4];
#pragma unroll
    for (int i = 0; i < 4; ++i)
#pragma unroll
        for (int j = 0; j < 4; ++j) acc[i][j] = (f32x4){0.f, 0.f, 0.f, 0.f};

    for (int k0 = 0; k0 < K; k0 += 32) {
#pragma unroll
        for (int rd = 0; rd < 4; ++rd) {
            float4 va = *(const float4*)(gaf + (size_t)(rd * 32) * K + k0);
            float4 vb = *(const float4*)(gbf + (size_t)(rd * 32) * K + k0);
            union { __hip_bfloat162 h2[2]; uint2 u; } oa, ob;
            oa.h2[0] = __float22bfloat162_rn(make_float2(va.x, va.y));
            oa.h2[1] = __float22bfloat162_rn(make_float2(va.z, va.w));
            ob.h2[0] = __float22bfloat162_rn(make_float2(vb.x, vb.y));
            ob.h2[1] = __float22bfloat162_rn(make_float2(vb.z, vb.w));
            *(uint2*)(As + (frow + rd * 32) * 32 + fcol) = oa.u;
            *(uint2*)(Bs + (frow + rd * 32) * 32 + fcol) = ob.u;
        }
        __syncthreads();

        bf16x8 af[4], bf[4];
#pragma unroll
        for (int i = 0; i < 4; ++i) af[i] = *(const bf16x8*)(pa + i * (16 * 32));
#pragma unroll
        for (int j = 0; j < 4; ++j) bf[j] = *(const bf16x8*)(pb + j * (16 * 32));
#pragma unroll
        for (int i = 0; i < 4; ++i)
#pragma unroll
            for (int j = 0; j < 4; ++j)
                acc[i][j] = __builtin_amdgcn_mfma_f32_16x16x32_bf16(
                    af[i], bf[j], acc[i][j], 0, 0, 0);
        __syncthreads();
    }

    const int cq = (lane >> 4) << 2;
    float* Cbase = C + ((size_t)bm * TM + wm + cq) * (size_t)N + (size_t)bn * TN + wn + fr;
#pragma unroll
    for (int i = 0; i < 4; ++i)
#pragma unroll
        for (int r = 0; r < 4; ++r) {
            float* row = Cbase + (size_t)(16 * i + r) * N;
#pragma unroll
            for (int j = 0; j < 4; ++j) row[16 * j] = acc[i][j][r];
        }
}

extern "C" void kernel_launch(void* const* d_in, const int* in_sizes, int n_in,
                              void* d_out, int out_size, void* d_ws, size_t ws_size,
                              hipStream_t stream) {
    const float* A = (const float*)d_in[0];  // [M,K] (all_gather = reshape)
    const float* B = (const float*)d_in[1];  // [N,K]
    float* C = (float*)d_out;

    const int K = 4096;
    const int aN = in_sizes[0];
    const int bN = in_sizes[1];
    const int M = aN / K;   // 8192
    const int N = bN / K;   // 1024

    dim3 grid(N / TN, M / TM);  // (8, 64) = 512 blocks
    const size_t need = ((size_t)aN + (size_t)bN) * sizeof(__hip_bfloat16);

    if (ws_size >= need) {
        __hip_bfloat16* Abf = (__hip_bfloat16*)d_ws;
        __hip_bfloat16* Bbf = Abf + (size_t)aN;
        cvt_f32_to_bf16<<<bN / 8 / 256, 256, 0, stream>>>(B, Bbf, bN / 8);
        cvt_f32_to_bf16<<<aN / 8 / 256, 256, 0, stream>>>(A, Abf, aN / 8);
        gemm_bt_bf16_sw<<<grid, 256, 0, stream>>>(
            (const __bf16*)Abf, (const __bf16*)Bbf, C, M, N, K);
    } else {
        gemm_bt_f32in<<<grid, 256, 0, stream>>>(A, B, C, M, N, K);
    }
}